// Round 1
// baseline (120.297 us; speedup 1.0000x reference)
//
#include <hip/hip_runtime.h>

#define N_TOT 4096
#define N_HALF 2048
#define DIMS 64
#define BATCH 4
// triangular block pairs per batch: sum_{ib=0}^{15} (32 - 2*ib) = 272
#define PAIRS_PER_BATCH 272

__device__ __forceinline__ const float* row_ptr(const float* __restrict__ x,
                                                const float* __restrict__ y,
                                                int b, int i) {
    return (i < N_HALF) ? (x + ((size_t)b * N_HALF + i) * DIMS)
                        : (y + ((size_t)b * N_HALF + (i - N_HALF)) * DIMS);
}

// Kernel A: per-row squared norms + per-batch sum of squared norms (double).
__global__ __launch_bounds__(256) void sq_kernel(const float* __restrict__ x,
                                                 const float* __restrict__ y,
                                                 float* __restrict__ sq,
                                                 double* __restrict__ Ssq) {
    int b = blockIdx.x >> 4;                       // 16 blocks per batch
    int r = ((blockIdx.x & 15) << 8) + threadIdx.x; // row in [0,4096)
    const float4* row = (const float4*)row_ptr(x, y, b, r);
    float s = 0.f;
#pragma unroll
    for (int k = 0; k < 16; ++k) {
        float4 v = row[k];
        s = fmaf(v.x, v.x, s);
        s = fmaf(v.y, v.y, s);
        s = fmaf(v.z, v.z, s);
        s = fmaf(v.w, v.w, s);
    }
    sq[b * N_TOT + r] = s;

    double ds = (double)s;
#pragma unroll
    for (int o = 32; o > 0; o >>= 1) ds += __shfl_down(ds, o);
    __shared__ double wred[4];
    int wid = threadIdx.x >> 6;
    if ((threadIdx.x & 63) == 0) wred[wid] = ds;
    __syncthreads();
    if (threadIdx.x == 0)
        atomicAdd(Ssq + b, wred[0] + wred[1] + wred[2] + wred[3]);
}

// Kernel B: per-batch per-dimension column sums (for analytic sum of L2).
__global__ __launch_bounds__(256) void colsum_kernel(const float* __restrict__ x,
                                                     const float* __restrict__ y,
                                                     double* __restrict__ colsum) {
    int b = blockIdx.x >> 4;
    int chunk = blockIdx.x & 15; // 256 rows per chunk
    const float* base = (chunk < 8)
        ? (x + ((size_t)b * N_HALF + chunk * 256) * DIMS)
        : (y + ((size_t)b * N_HALF + (chunk - 8) * 256) * DIMS);
    float part = 0.f;
    // flat = it*256 + tid -> col = tid & 63 (constant per thread)
    for (int it = 0; it < 64; ++it)
        part += base[it * 256 + threadIdx.x];
    __shared__ float p[256];
    p[threadIdx.x] = part;
    __syncthreads();
    if (threadIdx.x < 64) {
        float s = p[threadIdx.x] + p[threadIdx.x + 64] +
                  p[threadIdx.x + 128] + p[threadIdx.x + 192];
        atomicAdd(colsum + b * 64 + threadIdx.x, (double)s);
    }
}

// Kernel C: main pairwise kernel. Each thread owns one i-row in registers.
// j-rows are loop-uniform -> scalar loads. Triangular grid with weight
// 2 (j>i), 1 (j==i), 0 (j<i).
__global__ __launch_bounds__(256) void mmd_main(const float* __restrict__ x,
                                                const float* __restrict__ y,
                                                const float* __restrict__ sq,
                                                const double* __restrict__ Ssq,
                                                const double* __restrict__ colsum,
                                                double* __restrict__ loss) {
    int bx = blockIdx.x;
    int b = bx / PAIRS_PER_BATCH;
    int r = bx % PAIRS_PER_BATCH;
    // decode triangular (ib, jb): ib has (32 - 2*ib) j-chunks starting at jb=2*ib
    int ib = 0, cum = 0;
    while (r >= cum + (32 - 2 * ib)) { cum += 32 - 2 * ib; ++ib; }
    int jb = 2 * ib + (r - cum);
    int i0 = ib * 256, j0 = jb * 128;
    int i = i0 + threadIdx.x;

    // bandwidth from analytic sum(L2) = 2*N*Ssq - 2*||colsum||^2
    double s2 = 0.0;
#pragma unroll
    for (int dd = 0; dd < 64; ++dd) {
        double cv = colsum[b * 64 + dd];
        s2 += cv * cv;
    }
    double sumL2 = 2.0 * (double)N_TOT * Ssq[b] - 2.0 * s2;
    double bw = sumL2 / ((double)N_TOT * (double)N_TOT - (double)N_TOT);
    bw *= 0.25; // / KERNEL_MUL^(KERNEL_NUM//2) = / 4
    float c0 = (float)(-1.0 / bw);
    float c1 = 0.5f * c0, c2 = 0.25f * c0, c3 = 0.125f * c0, c4 = 0.0625f * c0;

    float4 a[16];
    const float4* arow = (const float4*)row_ptr(x, y, b, i);
#pragma unroll
    for (int k = 0; k < 16; ++k) a[k] = arow[k];
    float sqi = sq[b * N_TOT + i];
    float si = (i < N_HALF) ? 1.f : -1.f;

    double acc = 0.0;
    for (int jj = 0; jj < 128; ++jj) {
        int j = j0 + jj;
        const float4* brow = (const float4*)row_ptr(x, y, b, j); // uniform
        float dx = 0.f, dy = 0.f, dz = 0.f, dw = 0.f;
#pragma unroll
        for (int k = 0; k < 16; ++k) {
            float4 bv = brow[k];
            dx = fmaf(a[k].x, bv.x, dx);
            dy = fmaf(a[k].y, bv.y, dy);
            dz = fmaf(a[k].z, bv.z, dz);
            dw = fmaf(a[k].w, bv.w, dw);
        }
        float dot = (dx + dy) + (dz + dw);
        float L2 = sqi + sq[b * N_TOT + j] - 2.f * dot;
        float e = __expf(L2 * c0) + __expf(L2 * c1) + __expf(L2 * c2) +
                  __expf(L2 * c3) + __expf(L2 * c4);
        float wgt = (j > i) ? 2.f : ((j == i) ? 1.f : 0.f);
        float sj = (j < N_HALF) ? 1.f : -1.f;
        acc += (double)(wgt * si * sj * e);
    }

#pragma unroll
    for (int o = 32; o > 0; o >>= 1) acc += __shfl_down(acc, o);
    __shared__ double wred[4];
    int wid = threadIdx.x >> 6;
    if ((threadIdx.x & 63) == 0) wred[wid] = acc;
    __syncthreads();
    if (threadIdx.x == 0)
        atomicAdd(loss + b, wred[0] + wred[1] + wred[2] + wred[3]);
}

__global__ void finalize_kernel(const double* __restrict__ loss,
                                float* __restrict__ out) {
    int t = threadIdx.x;
    if (t < BATCH)
        out[t] = (float)(loss[t] / ((double)N_HALF * (double)N_HALF));
}

extern "C" void kernel_launch(void* const* d_in, const int* in_sizes, int n_in,
                              void* d_out, int out_size, void* d_ws, size_t ws_size,
                              hipStream_t stream) {
    const float* x = (const float*)d_in[0];
    const float* y = (const float*)d_in[1];
    float* out = (float*)d_out;
    char* ws = (char*)d_ws;

    double* Ssq    = (double*)ws;            // [0,   32): 4 doubles
    double* colsum = (double*)(ws + 64);     // [64, 2112): 4*64 doubles
    double* loss   = (double*)(ws + 2112);   // [2112, 2144): 4 doubles
    float*  sq     = (float*)(ws + 4096);    // [4096, 69632): 4*4096 floats

    // zero the atomic accumulators (ws is poisoned, not re-poisoned between replays)
    hipMemsetAsync(ws, 0, 2144, stream);

    sq_kernel<<<64, 256, 0, stream>>>(x, y, sq, Ssq);
    colsum_kernel<<<64, 256, 0, stream>>>(x, y, colsum);
    mmd_main<<<BATCH * PAIRS_PER_BATCH, 256, 0, stream>>>(x, y, sq, Ssq, colsum, loss);
    finalize_kernel<<<1, 64, 0, stream>>>(loss, out);
}

// Round 2
// 93.377 us; speedup vs baseline: 1.2883x; 1.2883x over previous
//
#include <hip/hip_runtime.h>

#define N_TOT 4096
#define N_HALF 2048
#define DIMS 64
#define BATCH 4
#define TGRID 32             // 4096 / 128 tile rows
#define PAIRS_PER_BATCH 528  // 32*33/2 triangular tiles

typedef __attribute__((ext_vector_type(8))) short short8;
typedef __attribute__((ext_vector_type(4))) float f32x4;

__device__ __forceinline__ unsigned short f2bf_rne(float f) {
    unsigned int u = __float_as_uint(f);
    unsigned int r = (u + 0x7FFFu + ((u >> 16) & 1u)) >> 16;
    return (unsigned short)r;
}
__device__ __forceinline__ float bf2f(unsigned short h) {
    return __uint_as_float(((unsigned int)h) << 16);
}

__device__ __forceinline__ const float* row_ptr(const float* __restrict__ x,
                                                const float* __restrict__ y,
                                                int b, int i) {
    return (i < N_HALF) ? (x + ((size_t)b * N_HALF + i) * DIMS)
                        : (y + ((size_t)b * N_HALF + (i - N_HALF)) * DIMS);
}

// Split each fp32 input element into bf16 hi + bf16 lo, stored concatenated
// as tot[b][4096][64]. 1024 blocks: [0,512) handle x, [512,1024) handle y.
__global__ __launch_bounds__(256) void convert_kernel(const float* __restrict__ x,
                                                      const float* __restrict__ y,
                                                      unsigned short* __restrict__ hi,
                                                      unsigned short* __restrict__ lo) {
    int g = blockIdx.x;
    const float* src;
    size_t dst;
    if (g < 512) {
        int e = (g << 10) + ((int)threadIdx.x << 2);
        src = x + e;
        int b = e >> 17;                 // 2048*64 = 131072 floats per batch
        int rem = e & 131071;
        dst = (size_t)b * 262144 + rem;  // tot batch stride 4096*64
    } else {
        int e = ((g - 512) << 10) + ((int)threadIdx.x << 2);
        src = y + e;
        int b = e >> 17;
        int rem = e & 131071;
        dst = (size_t)b * 262144 + 131072 + rem;
    }
    float4 v = *(const float4*)src;
    ushort4 h, l;
    h.x = f2bf_rne(v.x); l.x = f2bf_rne(v.x - bf2f(h.x));
    h.y = f2bf_rne(v.y); l.y = f2bf_rne(v.y - bf2f(h.y));
    h.z = f2bf_rne(v.z); l.z = f2bf_rne(v.z - bf2f(h.z));
    h.w = f2bf_rne(v.w); l.w = f2bf_rne(v.w - bf2f(h.w));
    *(ushort4*)(hi + dst) = h;
    *(ushort4*)(lo + dst) = l;
}

// Per-row squared norms (fp32 source) + per-batch sum (double).
__global__ __launch_bounds__(256) void sq_kernel(const float* __restrict__ x,
                                                 const float* __restrict__ y,
                                                 float* __restrict__ sq,
                                                 double* __restrict__ Ssq) {
    int b = blockIdx.x >> 4;
    int r = ((blockIdx.x & 15) << 8) + threadIdx.x;
    const float4* row = (const float4*)row_ptr(x, y, b, r);
    float s = 0.f;
#pragma unroll
    for (int k = 0; k < 16; ++k) {
        float4 v = row[k];
        s = fmaf(v.x, v.x, s);
        s = fmaf(v.y, v.y, s);
        s = fmaf(v.z, v.z, s);
        s = fmaf(v.w, v.w, s);
    }
    sq[b * N_TOT + r] = s;

    double ds = (double)s;
#pragma unroll
    for (int o = 32; o > 0; o >>= 1) ds += __shfl_down(ds, o);
    __shared__ double wred[4];
    int wid = threadIdx.x >> 6;
    if ((threadIdx.x & 63) == 0) wred[wid] = ds;
    __syncthreads();
    if (threadIdx.x == 0)
        atomicAdd(Ssq + b, wred[0] + wred[1] + wred[2] + wred[3]);
}

// Per-batch per-dimension column sums.
__global__ __launch_bounds__(256) void colsum_kernel(const float* __restrict__ x,
                                                     const float* __restrict__ y,
                                                     double* __restrict__ colsum) {
    int b = blockIdx.x >> 4;
    int chunk = blockIdx.x & 15;
    const float* base = (chunk < 8)
        ? (x + ((size_t)b * N_HALF + chunk * 256) * DIMS)
        : (y + ((size_t)b * N_HALF + (chunk - 8) * 256) * DIMS);
    float part = 0.f;
    for (int it = 0; it < 64; ++it)
        part += base[it * 256 + threadIdx.x];
    __shared__ float p[256];
    p[threadIdx.x] = part;
    __syncthreads();
    if (threadIdx.x < 64) {
        float s = p[threadIdx.x] + p[threadIdx.x + 64] +
                  p[threadIdx.x + 128] + p[threadIdx.x + 192];
        atomicAdd(colsum + b * 64 + threadIdx.x, (double)s);
    }
}

// bandwidth -> 5 exp2 coefficients per batch: k_i = -log2(e) / bw_i
__global__ void bw_setup(const double* __restrict__ Ssq,
                         const double* __restrict__ colsum,
                         float* __restrict__ kcoef) {
    int b = threadIdx.x;
    if (b >= BATCH) return;
    double s2 = 0.0;
    for (int d = 0; d < 64; ++d) {
        double cv = colsum[b * 64 + d];
        s2 += cv * cv;
    }
    double sumL2 = 2.0 * (double)N_TOT * Ssq[b] - 2.0 * s2;
    double bw = sumL2 / ((double)N_TOT * (double)N_TOT - (double)N_TOT);
    bw *= 0.25;  // / KERNEL_MUL^(KERNEL_NUM//2)
    const double log2e = 1.4426950408889634;
    for (int i = 0; i < 5; ++i)
        kcoef[b * 5 + i] = (float)(-log2e / (bw * (double)(1 << i)));
}

// Main: triangular 128x128 tiles, 4 waves of 64x64, split-bf16 3-pass MFMA,
// fused exp epilogue. Operands loaded directly from L2-resident bf16 arrays.
__global__ __launch_bounds__(256) void mmd_mfma(const unsigned short* __restrict__ hi,
                                                const unsigned short* __restrict__ lo,
                                                const float* __restrict__ sq,
                                                const float* __restrict__ kcoef,
                                                double* __restrict__ loss) {
    int wg = blockIdx.x;
    int b = wg / PAIRS_PER_BATCH;
    int r = wg % PAIRS_PER_BATCH;
    int ib = 0, cum = 0;
    while (r >= cum + (TGRID - ib)) { cum += TGRID - ib; ++ib; }
    int jb = ib + (r - cum);

    int wid = threadIdx.x >> 6, lane = threadIdx.x & 63;
    int wr = wid >> 1, wc = wid & 1;
    int i_base = ib * 128 + wr * 64;
    int j_base = jb * 128 + wc * 64;

    const unsigned short* Hb = hi + (size_t)b * 262144;
    const unsigned short* Lb = lo + (size_t)b * 262144;
    int lrow = lane & 15;          // A row / B col within 16
    int kblk = (lane >> 4) * 8;    // k sub-block

    f32x4 acc[4][4];
#pragma unroll
    for (int mf = 0; mf < 4; ++mf)
#pragma unroll
        for (int nf = 0; nf < 4; ++nf)
            acc[mf][nf] = (f32x4){0.f, 0.f, 0.f, 0.f};

#pragma unroll
    for (int ks = 0; ks < 2; ++ks) {
        short8 ah[4], al[4], bh[4], bl[4];
        int ko = ks * 32 + kblk;
#pragma unroll
        for (int f = 0; f < 4; ++f) {
            size_t ra = (size_t)(i_base + f * 16 + lrow) * DIMS + ko;
            size_t rb = (size_t)(j_base + f * 16 + lrow) * DIMS + ko;
            ah[f] = *(const short8*)(Hb + ra);
            al[f] = *(const short8*)(Lb + ra);
            bh[f] = *(const short8*)(Hb + rb);
            bl[f] = *(const short8*)(Lb + rb);
        }
#pragma unroll
        for (int mf = 0; mf < 4; ++mf)
#pragma unroll
            for (int nf = 0; nf < 4; ++nf) {
                acc[mf][nf] = __builtin_amdgcn_mfma_f32_16x16x32_bf16(ah[mf], bh[nf], acc[mf][nf], 0, 0, 0);
                acc[mf][nf] = __builtin_amdgcn_mfma_f32_16x16x32_bf16(ah[mf], bl[nf], acc[mf][nf], 0, 0, 0);
                acc[mf][nf] = __builtin_amdgcn_mfma_f32_16x16x32_bf16(al[mf], bh[nf], acc[mf][nf], 0, 0, 0);
            }
    }

    float k0 = kcoef[b * 5 + 0], k1 = kcoef[b * 5 + 1], k2 = kcoef[b * 5 + 2],
          k3 = kcoef[b * 5 + 3], k4 = kcoef[b * 5 + 4];
    const float* sqb = sq + b * N_TOT;
    int rquad = (lane >> 4) * 4;  // C layout: row = (lane>>4)*4 + reg

    float sqi[4][4], sqjv[4];
#pragma unroll
    for (int mf = 0; mf < 4; ++mf)
#pragma unroll
        for (int rg = 0; rg < 4; ++rg)
            sqi[mf][rg] = sqb[i_base + mf * 16 + rquad + rg];
#pragma unroll
    for (int nf = 0; nf < 4; ++nf)
        sqjv[nf] = sqb[j_base + nf * 16 + lrow];

    float accf = 0.f;
#pragma unroll
    for (int mf = 0; mf < 4; ++mf)
#pragma unroll
        for (int nf = 0; nf < 4; ++nf) {
            int j = j_base + nf * 16 + lrow;
            float sj = (j < N_HALF) ? 1.f : -1.f;
#pragma unroll
            for (int rg = 0; rg < 4; ++rg) {
                int i = i_base + mf * 16 + rquad + rg;
                float dot = acc[mf][nf][rg];
                float L2 = sqi[mf][rg] + sqjv[nf] - 2.f * dot;
                float e = exp2f(L2 * k0) + exp2f(L2 * k1) + exp2f(L2 * k2) +
                          exp2f(L2 * k3) + exp2f(L2 * k4);
                float w = (j > i) ? 2.f : ((j == i) ? 1.f : 0.f);
                float si = (i < N_HALF) ? 1.f : -1.f;
                accf += w * si * sj * e;
            }
        }

    double acc_d = (double)accf;
#pragma unroll
    for (int o = 32; o > 0; o >>= 1) acc_d += __shfl_down(acc_d, o);
    __shared__ double wred[4];
    if ((threadIdx.x & 63) == 0) wred[wid] = acc_d;
    __syncthreads();
    if (threadIdx.x == 0)
        atomicAdd(loss + b, wred[0] + wred[1] + wred[2] + wred[3]);
}

__global__ void finalize_kernel(const double* __restrict__ loss,
                                float* __restrict__ out) {
    int t = threadIdx.x;
    if (t < BATCH)
        out[t] = (float)(loss[t] / ((double)N_HALF * (double)N_HALF));
}

extern "C" void kernel_launch(void* const* d_in, const int* in_sizes, int n_in,
                              void* d_out, int out_size, void* d_ws, size_t ws_size,
                              hipStream_t stream) {
    const float* x = (const float*)d_in[0];
    const float* y = (const float*)d_in[1];
    float* out = (float*)d_out;
    char* ws = (char*)d_ws;

    double* Ssq    = (double*)ws;                    // [0, 32)
    double* colsum = (double*)(ws + 64);             // [64, 2112)
    double* loss   = (double*)(ws + 2112);           // [2112, 2144)
    float*  kcoef  = (float*)(ws + 2176);            // [2176, 2256)
    float*  sq     = (float*)(ws + 4096);            // [4096, 69632)
    unsigned short* tot_hi = (unsigned short*)(ws + 69632);    // 2 MB
    unsigned short* tot_lo = (unsigned short*)(ws + 2166784);  // 2 MB

    hipMemsetAsync(ws, 0, 2144, stream);

    convert_kernel<<<1024, 256, 0, stream>>>(x, y, tot_hi, tot_lo);
    sq_kernel<<<64, 256, 0, stream>>>(x, y, sq, Ssq);
    colsum_kernel<<<64, 256, 0, stream>>>(x, y, colsum);
    bw_setup<<<1, 64, 0, stream>>>(Ssq, colsum, kcoef);
    mmd_mfma<<<BATCH * PAIRS_PER_BATCH, 256, 0, stream>>>(tot_hi, tot_lo, sq, kcoef, loss);
    finalize_kernel<<<1, 64, 0, stream>>>(loss, out);
}